// Round 19
// baseline (234.974 us; speedup 1.0000x reference)
//
#include <hip/hip_runtime.h>
#include <hip/hip_bf16.h>
#include <stdint.h>

typedef __attribute__((ext_vector_type(4))) int i32x4;
typedef __attribute__((ext_vector_type(16))) int i32x16;
typedef signed char s8;

#define M_TOT 8192
#define N_TOT 8192
#define K_TOT 2048
#define W_COUNT (N_TOT * K_TOT)
#define X_COUNT (M_TOT * K_TOT)

// ---------------- 1. fused deterministic reductions: sum|w| (double), max|x| ----------
__global__ void tl_reduce(const float* __restrict__ w, const float* __restrict__ x,
                          double* __restrict__ wsum, float* __restrict__ xmax) {
    const int b = blockIdx.x;
    if (b < 1024) {
        const int tid = b * 256 + threadIdx.x;
        const float4* w4 = (const float4*)w;
        double s = 0.0;
        for (int i = tid; i < W_COUNT / 4; i += 1024 * 256) {
            float4 v = w4[i];
            s += (double)fabsf(v.x) + (double)fabsf(v.y) + (double)fabsf(v.z) + (double)fabsf(v.w);
        }
        #pragma unroll
        for (int off = 32; off > 0; off >>= 1) s += __shfl_down(s, off);
        __shared__ double red[4];
        if ((threadIdx.x & 63) == 0) red[threadIdx.x >> 6] = s;
        __syncthreads();
        if (threadIdx.x == 0) wsum[b] = (red[0] + red[1]) + (red[2] + red[3]);
    } else {
        const int tid = (b - 1024) * 256 + threadIdx.x;
        const float4* x4 = (const float4*)x;
        float m = 0.0f;
        for (int i = tid; i < X_COUNT / 4; i += 1024 * 256) {
            float4 v = x4[i];
            m = fmaxf(m, fmaxf(fmaxf(fabsf(v.x), fabsf(v.y)), fmaxf(fabsf(v.z), fabsf(v.w))));
        }
        #pragma unroll
        for (int off = 32; off > 0; off >>= 1) m = fmaxf(m, __shfl_down(m, off));
        __shared__ float redm[4];
        if ((threadIdx.x & 63) == 0) redm[threadIdx.x >> 6] = m;
        __syncthreads();
        if (threadIdx.x == 0) xmax[b - 1024] = fmaxf(fmaxf(redm[0], redm[1]), fmaxf(redm[2], redm[3]));
    }
}

__global__ void tl_finalize(const double* __restrict__ wsum, const float* __restrict__ xmax,
                            const float* __restrict__ alpha,
                            double* __restrict__ delta, float* __restrict__ qp) {
    const int t = threadIdx.x;
    double s = (wsum[t] + wsum[t + 256]) + (wsum[t + 512] + wsum[t + 768]);
    float m = fmaxf(fmaxf(xmax[t], xmax[t + 256]), fmaxf(xmax[t + 512], xmax[t + 768]));
    #pragma unroll
    for (int off = 32; off > 0; off >>= 1) {
        s += __shfl_down(s, off);
        m = fmaxf(m, __shfl_down(m, off));
    }
    __shared__ double rs[4];
    __shared__ float rm[4];
    if ((t & 63) == 0) { rs[t >> 6] = s; rm[t >> 6] = m; }
    __syncthreads();
    if (t == 0) {
        *delta = 0.7 * (((rs[0] + rs[1]) + (rs[2] + rs[3])) / (double)W_COUNT);
        float mm = fmaxf(fmaxf(rm[0], rm[1]), fmaxf(rm[2], rm[3]));
        qp[0] = 127.0f / mm;                   // x quant scale
        qp[1] = alpha[0] * (mm / 127.0f);      // output scale
    }
}

// ---------------- 2. fused quantize: w -> ternary i8, x -> i8 (one dispatch) --------
__global__ void tl_quant(const float* __restrict__ w, const float* __restrict__ x,
                         const double* __restrict__ delta_p, const float* __restrict__ qp,
                         s8* __restrict__ wb, s8* __restrict__ xb) {
    const int b = blockIdx.x;
    if (b < 4096) {
        const double d = *delta_p;
        const int i = (b * 256 + threadIdx.x) * 16;
        union { s8 c[16]; i32x4 v; } o;
        #pragma unroll
        for (int j = 0; j < 16; j += 4) {
            float4 v = *(const float4*)(w + i + j);
            float f[4] = {v.x, v.y, v.z, v.w};
            #pragma unroll
            for (int r = 0; r < 4; ++r) {
                double wd = (double)f[r];
                o.c[j + r] = wd > d ? 1 : (wd < -d ? -1 : 0);
            }
        }
        *(i32x4*)(wb + i) = o.v;
    } else {
        const float inv = qp[0];
        const int i = ((b - 4096) * 256 + threadIdx.x) * 16;
        union { s8 c[16]; i32x4 v; } o;
        #pragma unroll
        for (int j = 0; j < 16; j += 4) {
            float4 v = *(const float4*)(x + i + j);
            float f[4] = {v.x, v.y, v.z, v.w};
            #pragma unroll
            for (int r = 0; r < 4; ++r) {
                int q = (int)__builtin_rintf(f[r] * inv);
                q = q > 127 ? 127 : (q < -127 ? -127 : q);
                o.c[j + r] = (s8)q;
            }
        }
        *(i32x4*)(xb + i) = o.v;
    }
}

// ---------------- 3. i8 MFMA GEMM: 64x32 wave tiles, target 6 waves/SIMD -----------
// C[m][n] = out_scale * (sum_k xq[m][k]*wt[n][k]) + bias[n]
// Block tile 128x128, 512 threads = 8 waves (2 wr x 4 wc), wave owns 64x32 =
// 2x1 32x32 frags -> acc 32 AGPR, total ~80 regs: __launch_bounds__(512,6)
// = 6 waves/SIMD = 24 waves/CU = 3 blocks/CU (reg cap). LDS 48 KiB (3 blocks
// x 48K = 144K <= 160K): A slots s*8K (0..24K), B slots 24K + s*8K.
// r7/r18 skeleton scaled: RD3(h1); lgkm(3); MM2(h0); stage t+2 (2 glds);
// lgkm(0); VMW(2) counted gate; BARR; RD3(next h0); MM2(h1). No setprio.

#define SB    __builtin_amdgcn_sched_barrier(0)
#define BARR  __builtin_amdgcn_s_barrier()
#define LGKM3 asm volatile("s_waitcnt lgkmcnt(3)" ::: "memory")
#define LGKM0 asm volatile("s_waitcnt lgkmcnt(0)" ::: "memory")
#define VMW(N) asm volatile("s_waitcnt vmcnt(" #N ")" ::: "memory")

#define GLDS(SRC, DOFF) __builtin_amdgcn_global_load_lds(                      \
    (const __attribute__((address_space(1))) void*)(SRC),                      \
    (__attribute__((address_space(3))) void*)(lds + (DOFF)), 16, 0, 0)

// 3 reads (2 A + 1 B) for k-half KK of slot S
#define RD3(AR, BR_, S, KK) do {                                               \
    AR[0] = *(const i32x4*)(lds + (S) * 8192 + wrOff + 0 * 2048 +              \
                            (lrd ^ ((KK) * 32)));                              \
    AR[1] = *(const i32x4*)(lds + (S) * 8192 + wrOff + 1 * 2048 +              \
                            (lrd ^ ((KK) * 32)));                              \
    BR_ = *(const i32x4*)(lds + 24576 + (S) * 8192 + wcOff +                   \
                          (lrd ^ ((KK) * 32)));                                \
} while (0)

#define MM2(AR, BR_) do {                                                      \
    acc[0] = __builtin_amdgcn_mfma_i32_32x32x32_i8(AR[0], BR_, acc[0], 0, 0, 0); \
    acc[1] = __builtin_amdgcn_mfma_i32_32x32x32_i8(AR[1], BR_, acc[1], 0, 0, 0); \
} while (0)

// A slot 8KB = 1 glds call (512 thr x 16B); B slot 8KB = 1 call
#define STG_A(SS, KOFF) GLDS(aSrc + (KOFF), (SS) * 8192 + L)
#define STG_B(SS, KOFF) GLDS(bSrc + (KOFF), 24576 + (SS) * 8192 + L)

// Entering invariant: 3 ds_reads (aE/bE = h0 of slot S) in flight;
// vm queue = [stg(t+1) 2].
#define KTILE(S, SN, SG, KOFF, DOSTG, GATE, DONEXT) do {                       \
    RD3(aO, bO, S, 1);                                                         \
    LGKM3; SB;                                                                 \
    MM2(aE, bE);                                                               \
    if (DOSTG) { STG_A(SG, KOFF); STG_B(SG, KOFF); }                           \
    LGKM0; SB;                                                                 \
    GATE; SB;                                                                  \
    BARR;                                                                      \
    if (DONEXT) RD3(aE, bE, SN, 0);                                            \
    MM2(aO, bO);                                                               \
} while (0)

__global__ __launch_bounds__(512, 6) void tl_gemm_i8(
    const s8* __restrict__ A, const s8* __restrict__ Bm,
    const float* __restrict__ qp, const float* __restrict__ bias,
    float* __restrict__ C) {
    __shared__ __attribute__((aligned(128))) char lds[49152];  // 48 KiB

    const int t = threadIdx.x;
    const int wid = t >> 6;
    const int l = t & 63;
    const int wr = wid >> 2;   // 0..1
    const int wc = wid & 3;    // 0..3

    // XCD rect: 4096 blocks; per XCD j=0..511: 8tm x 16tn panels (bijective)
    const int bid = blockIdx.x;
    const int xc = bid & 7;
    const int j = bid >> 3;                         // 0..511
    const int tm = xc * 8 + ((j >> 4) & 7);         // 0..63
    const int tn = (j & 15) + ((j >> 7) << 4);      // 0..63
    const int row0 = tm * 128, col0 = tn * 128;

    // staging coords: linear dest byte L holds logical off = L^(((L>>7)&3)<<4)
    const int L = t * 16;                 // 0..8191
    const int off = L ^ (((L >> 7) & 3) << 4);
    const int sr = off >> 6;              // 0..127
    const int kb = off & 63;              // 16-aligned k-byte
    const s8* aSrc = A + (size_t)(row0 + sr) * K_TOT + kb;
    const s8* bSrc = Bm + (size_t)(col0 + sr) * K_TOT + kb;

    // ds_read lane constants (32x32 fragment: row = l&31, k-group = l>>5)
    const int rl = l & 31, kg = l >> 5;
    const int lrd = rl * 64 + ((kg ^ ((rl >> 1) & 3)) << 4);
    const int wrOff = wr * 4096;      // 64 rows * 64 B (A slot)
    const int wcOff = wc * 2048;      // 32 rows * 64 B (B slot)

    i32x16 acc[2] = {};
    i32x4 aE[2], aO[2], bE, bO;

    // prologue: stage tiles 0 (slot0) and 1 (slot1); gate tile0; first h0 reads
    STG_A(0, 0); STG_B(0, 0);
    STG_A(1, 64); STG_B(1, 64);
    VMW(2); SB; BARR;
    RD3(aE, bE, 0, 0);

    int koff = 128;   // staging byte offset for tile t+2
    #pragma unroll 1
    for (int i = 0; i < 10; ++i) {
        KTILE(0, 1, 2, koff, 1, VMW(2), 1); koff += 64;
        KTILE(1, 2, 0, koff, 1, VMW(2), 1); koff += 64;
        KTILE(2, 0, 1, koff, 1, VMW(2), 1); koff += 64;
    }
    KTILE(0, 1, 0, 0, 0, VMW(0), 1);    // tile 30: drain t31 staging, read its h0
    KTILE(1, 0, 0, 0, 0, (void)0, 0);   // tile 31

    // epilogue: C = out_scale * acc + bias
    // 32x32 C/D layout: col = l&31, row = (reg&3) + 8*(reg>>2) + 4*(l>>5)
    const float osc = qp[1];
    const int ccol = col0 + wc * 32 + rl;
    const float bv = bias[ccol];
    #pragma unroll
    for (int m_ = 0; m_ < 2; ++m_) {
        const int crow = row0 + wr * 64 + m_ * 32 + kg * 4;
        #pragma unroll
        for (int r = 0; r < 16; ++r) {
            const int row = crow + (r & 3) + 8 * (r >> 2);
            C[(size_t)row * N_TOT + ccol] = (float)acc[m_][r] * osc + bv;
        }
    }
}

extern "C" void kernel_launch(void* const* d_in, const int* in_sizes, int n_in,
                              void* d_out, int out_size, void* d_ws, size_t ws_size,
                              hipStream_t stream) {
    const float* x     = (const float*)d_in[0];
    const float* wgt   = (const float*)d_in[1];
    const float* alpha = (const float*)d_in[2];
    const float* bias  = (const float*)d_in[3];
    float* out = (float*)d_out;

    char* ws = (char*)d_ws;
    double* wsum = (double*)ws;               // 8 KB
    float* xmax  = (float*)(ws + 8192);       // 4 KB
    double* delta = (double*)(ws + 12288);
    float* qp     = (float*)(ws + 12304);     // [0]=127/max, [1]=alpha*max/127
    s8* xb = (s8*)(ws + 16384);               // 16 MB, row-major
    s8* wb = (s8*)(ws + 16384 + (size_t)X_COUNT);  // 16 MB, row-major

    tl_reduce<<<2048, 256, 0, stream>>>(wgt, x, wsum, xmax);
    tl_finalize<<<1, 256, 0, stream>>>(wsum, xmax, alpha, delta, qp);
    tl_quant<<<8192, 256, 0, stream>>>(wgt, x, delta, qp, wb, xb);
    tl_gemm_i8<<<(M_TOT / 128) * (N_TOT / 128), 512, 0, stream>>>(xb, wb, qp, bias, out);
}

// Round 20
// 200.496 us; speedup vs baseline: 1.1720x; 1.1720x over previous
//
#include <hip/hip_runtime.h>
#include <hip/hip_bf16.h>
#include <stdint.h>

typedef __attribute__((ext_vector_type(4))) int i32x4;
typedef __attribute__((ext_vector_type(16))) int i32x16;
typedef signed char s8;

#define M_TOT 8192
#define N_TOT 8192
#define K_TOT 2048
#define W_COUNT (N_TOT * K_TOT)
#define X_COUNT (M_TOT * K_TOT)

// ---------------- 1. fused deterministic reductions: sum|w| (double), max|x| ----------
__global__ void tl_reduce(const float* __restrict__ w, const float* __restrict__ x,
                          double* __restrict__ wsum, float* __restrict__ xmax) {
    const int b = blockIdx.x;
    if (b < 1024) {
        const int tid = b * 256 + threadIdx.x;
        const float4* w4 = (const float4*)w;
        double s = 0.0;
        for (int i = tid; i < W_COUNT / 4; i += 1024 * 256) {
            float4 v = w4[i];
            s += (double)fabsf(v.x) + (double)fabsf(v.y) + (double)fabsf(v.z) + (double)fabsf(v.w);
        }
        #pragma unroll
        for (int off = 32; off > 0; off >>= 1) s += __shfl_down(s, off);
        __shared__ double red[4];
        if ((threadIdx.x & 63) == 0) red[threadIdx.x >> 6] = s;
        __syncthreads();
        if (threadIdx.x == 0) wsum[b] = (red[0] + red[1]) + (red[2] + red[3]);
    } else {
        const int tid = (b - 1024) * 256 + threadIdx.x;
        const float4* x4 = (const float4*)x;
        float m = 0.0f;
        for (int i = tid; i < X_COUNT / 4; i += 1024 * 256) {
            float4 v = x4[i];
            m = fmaxf(m, fmaxf(fmaxf(fabsf(v.x), fabsf(v.y)), fmaxf(fabsf(v.z), fabsf(v.w))));
        }
        #pragma unroll
        for (int off = 32; off > 0; off >>= 1) m = fmaxf(m, __shfl_down(m, off));
        __shared__ float redm[4];
        if ((threadIdx.x & 63) == 0) redm[threadIdx.x >> 6] = m;
        __syncthreads();
        if (threadIdx.x == 0) xmax[b - 1024] = fmaxf(fmaxf(redm[0], redm[1]), fmaxf(redm[2], redm[3]));
    }
}

__global__ void tl_finalize(const double* __restrict__ wsum, const float* __restrict__ xmax,
                            const float* __restrict__ alpha,
                            double* __restrict__ delta, float* __restrict__ qp) {
    const int t = threadIdx.x;
    double s = (wsum[t] + wsum[t + 256]) + (wsum[t + 512] + wsum[t + 768]);
    float m = fmaxf(fmaxf(xmax[t], xmax[t + 256]), fmaxf(xmax[t + 512], xmax[t + 768]));
    #pragma unroll
    for (int off = 32; off > 0; off >>= 1) {
        s += __shfl_down(s, off);
        m = fmaxf(m, __shfl_down(m, off));
    }
    __shared__ double rs[4];
    __shared__ float rm[4];
    if ((t & 63) == 0) { rs[t >> 6] = s; rm[t >> 6] = m; }
    __syncthreads();
    if (t == 0) {
        *delta = 0.7 * (((rs[0] + rs[1]) + (rs[2] + rs[3])) / (double)W_COUNT);
        float mm = fmaxf(fmaxf(rm[0], rm[1]), fmaxf(rm[2], rm[3]));
        qp[0] = 127.0f / mm;                   // x quant scale
        qp[1] = alpha[0] * (mm / 127.0f);      // output scale
    }
}

// ---------------- 2. fused quantize: w -> ternary i8, x -> i8 (one dispatch) --------
__global__ void tl_quant(const float* __restrict__ w, const float* __restrict__ x,
                         const double* __restrict__ delta_p, const float* __restrict__ qp,
                         s8* __restrict__ wb, s8* __restrict__ xb) {
    const int b = blockIdx.x;
    if (b < 4096) {
        const double d = *delta_p;
        const int i = (b * 256 + threadIdx.x) * 16;
        union { s8 c[16]; i32x4 v; } o;
        #pragma unroll
        for (int j = 0; j < 16; j += 4) {
            float4 v = *(const float4*)(w + i + j);
            float f[4] = {v.x, v.y, v.z, v.w};
            #pragma unroll
            for (int r = 0; r < 4; ++r) {
                double wd = (double)f[r];
                o.c[j + r] = wd > d ? 1 : (wd < -d ? -1 : 0);
            }
        }
        *(i32x4*)(wb + i) = o.v;
    } else {
        const float inv = qp[0];
        const int i = ((b - 4096) * 256 + threadIdx.x) * 16;
        union { s8 c[16]; i32x4 v; } o;
        #pragma unroll
        for (int j = 0; j < 16; j += 4) {
            float4 v = *(const float4*)(x + i + j);
            float f[4] = {v.x, v.y, v.z, v.w};
            #pragma unroll
            for (int r = 0; r < 4; ++r) {
                int q = (int)__builtin_rintf(f[r] * inv);
                q = q > 127 ? 127 : (q < -127 ? -127 : q);
                o.c[j + r] = (s8)q;
            }
        }
        *(i32x4*)(xb + i) = o.v;
    }
}

// ---------------- 3. i8 MFMA GEMM: 256x256 block, 16 waves, 4 waves/SIMD -----------
// C[m][n] = out_scale * (sum_k xq[m][k]*wt[n][k]) + bias[n]
// 1024 threads = 16 waves (4 wr x 4 wc); wave owns 64x64 = 2x2 32x32 frags
// (acc 64 AGPR, ~115 regs -> __launch_bounds__(1024,4) keeps 4 waves/SIMD,
// r18's proven occupancy). One block/CU @ 96 KiB LDS (A/B 3x16K slots).
// vs r18: staged bytes/MAC halved (32 KB vs 48 KB per CU-step), glds 2/tile
// (full 16 KB slot per call), FETCH back to ~98 MB. K-loop = proven skeleton:
// RD4(h1); lgkm(4); MM4(h0); stage t+2 (2 glds); lgkm(0); VMW(2) gate; BARR;
// RD4(next h0); MM4(h1). No setprio.

#define SB    __builtin_amdgcn_sched_barrier(0)
#define BARR  __builtin_amdgcn_s_barrier()
#define LGKM4 asm volatile("s_waitcnt lgkmcnt(4)" ::: "memory")
#define LGKM0 asm volatile("s_waitcnt lgkmcnt(0)" ::: "memory")
#define VMW(N) asm volatile("s_waitcnt vmcnt(" #N ")" ::: "memory")

#define GLDS(SRC, DOFF) __builtin_amdgcn_global_load_lds(                      \
    (const __attribute__((address_space(1))) void*)(SRC),                      \
    (__attribute__((address_space(3))) void*)(lds + (DOFF)), 16, 0, 0)

// 4 reads (2 A + 2 B) for k-half KK of slot S
#define RD4(AR, BR, S, KK) do {                                                \
    _Pragma("unroll") for (int m_ = 0; m_ < 2; ++m_)                           \
        AR[m_] = *(const i32x4*)(lds + (S) * 16384 + wrOff + m_ * 2048 +       \
                                 (lrd ^ ((KK) * 32)));                         \
    _Pragma("unroll") for (int n_ = 0; n_ < 2; ++n_)                           \
        BR[n_] = *(const i32x4*)(lds + 49152 + (S) * 16384 + wcOff + n_ * 2048 + \
                                 (lrd ^ ((KK) * 32)));                         \
} while (0)

#define MM4(AR, BR) do {                                                       \
    _Pragma("unroll") for (int m_ = 0; m_ < 2; ++m_)                           \
    _Pragma("unroll") for (int n_ = 0; n_ < 2; ++n_)                           \
        acc[m_][n_] = __builtin_amdgcn_mfma_i32_32x32x32_i8(                   \
            AR[m_], BR[n_], acc[m_][n_], 0, 0, 0);                             \
} while (0)

// slot = 256 rows x 64 B = 16 KB = ONE glds call at 1024 thr x 16 B
#define STG_A(SS, KOFF) GLDS(aSrc + (KOFF), (SS) * 16384 + L)
#define STG_B(SS, KOFF) GLDS(bSrc + (KOFF), 49152 + (SS) * 16384 + L)

// Entering invariant: 4 ds_reads (aE/bE = h0 of slot S) in flight;
// vm queue = [stg(t+1) 2].
#define KTILE(S, SN, SG, KOFF, DOSTG, GATE, DONEXT) do {                       \
    RD4(aO, bO, S, 1);                                                         \
    LGKM4; SB;                                                                 \
    MM4(aE, bE);                                                               \
    if (DOSTG) { STG_A(SG, KOFF); STG_B(SG, KOFF); }                           \
    LGKM0; SB;                                                                 \
    GATE; SB;                                                                  \
    BARR;                                                                      \
    if (DONEXT) RD4(aE, bE, SN, 0);                                            \
    MM4(aO, bO);                                                               \
} while (0)

__global__ __launch_bounds__(1024, 4) void tl_gemm_i8(
    const s8* __restrict__ A, const s8* __restrict__ Bm,
    const float* __restrict__ qp, const float* __restrict__ bias,
    float* __restrict__ C) {
    __shared__ __attribute__((aligned(128))) char lds[98304];  // 96 KiB

    const int t = threadIdx.x;
    const int wid = t >> 6;
    const int l = t & 63;
    const int wr = wid >> 2;   // 0..3
    const int wc = wid & 3;    // 0..3

    // rect XCD ordering: resident 32 blocks/XCD = 4tm x 8tn rectangle (r7)
    const int bid = blockIdx.x;
    const int xc = bid & 7;
    const int j = bid >> 3;                       // 0..127
    const int tm = xc * 4 + ((j >> 3) & 3);
    const int tn = (j >> 5) * 8 + (j & 7);
    const int row0 = tm * 256, col0 = tn * 256;

    // staging coords: linear dest byte L (0..16383) holds logical
    // off = L ^ (((L>>7)&3)<<4)  (col-chunk ^= (row>>1)&3, involution)
    const int L = t * 16;
    const int off = L ^ (((L >> 7) & 3) << 4);
    const int sr = off >> 6;          // 0..255 (full slot rows)
    const int kb = off & 63;          // 16-aligned k-byte
    const s8* aSrc = A + (size_t)(row0 + sr) * K_TOT + kb;
    const s8* bSrc = Bm + (size_t)(col0 + sr) * K_TOT + kb;

    // ds_read lane constants (32x32 fragment: row = l&31, k-group = l>>5)
    const int rl = l & 31, kg = l >> 5;
    const int lrd = rl * 64 + ((kg ^ ((rl >> 1) & 3)) << 4);
    const int wrOff = wr * 4096;      // 64 rows * 64 B (A slot)
    const int wcOff = wc * 4096;      // 64 rows * 64 B (B slot)

    i32x16 acc[2][2] = {};
    i32x4 aE[2], bE[2], aO[2], bO[2];

    // prologue: stage tiles 0 (slot0) and 1 (slot1); gate tile0; first h0 reads
    STG_A(0, 0); STG_B(0, 0);
    STG_A(1, 64); STG_B(1, 64);
    VMW(2); SB; BARR;
    RD4(aE, bE, 0, 0);

    int koff = 128;   // staging byte offset for tile t+2
    #pragma unroll 1
    for (int i = 0; i < 10; ++i) {
        KTILE(0, 1, 2, koff, 1, VMW(2), 1); koff += 64;
        KTILE(1, 2, 0, koff, 1, VMW(2), 1); koff += 64;
        KTILE(2, 0, 1, koff, 1, VMW(2), 1); koff += 64;
    }
    KTILE(0, 1, 0, 0, 0, VMW(0), 1);    // tile 30: drain t31 staging, read its h0
    KTILE(1, 0, 0, 0, 0, (void)0, 0);   // tile 31

    // epilogue: C = out_scale * acc + bias
    // 32x32 C/D layout: col = l&31, row = (reg&3) + 8*(reg>>2) + 4*(l>>5)
    const float osc = qp[1];
    #pragma unroll
    for (int m_ = 0; m_ < 2; ++m_) {
        const int crow = row0 + wr * 64 + m_ * 32 + kg * 4;
        #pragma unroll
        for (int n_ = 0; n_ < 2; ++n_) {
            const int ccol = col0 + wc * 64 + n_ * 32 + rl;
            const float bv = bias[ccol];
            #pragma unroll
            for (int r = 0; r < 16; ++r) {
                const int row = crow + (r & 3) + 8 * (r >> 2);
                C[(size_t)row * N_TOT + ccol] = (float)acc[m_][n_][r] * osc + bv;
            }
        }
    }
}

extern "C" void kernel_launch(void* const* d_in, const int* in_sizes, int n_in,
                              void* d_out, int out_size, void* d_ws, size_t ws_size,
                              hipStream_t stream) {
    const float* x     = (const float*)d_in[0];
    const float* wgt   = (const float*)d_in[1];
    const float* alpha = (const float*)d_in[2];
    const float* bias  = (const float*)d_in[3];
    float* out = (float*)d_out;

    char* ws = (char*)d_ws;
    double* wsum = (double*)ws;               // 8 KB
    float* xmax  = (float*)(ws + 8192);       // 4 KB
    double* delta = (double*)(ws + 12288);
    float* qp     = (float*)(ws + 12304);     // [0]=127/max, [1]=alpha*max/127
    s8* xb = (s8*)(ws + 16384);               // 16 MB, row-major
    s8* wb = (s8*)(ws + 16384 + (size_t)X_COUNT);  // 16 MB, row-major

    tl_reduce<<<2048, 256, 0, stream>>>(wgt, x, wsum, xmax);
    tl_finalize<<<1, 256, 0, stream>>>(wsum, xmax, alpha, delta, qp);
    tl_quant<<<8192, 256, 0, stream>>>(wgt, x, delta, qp, wb, xb);
    tl_gemm_i8<<<(M_TOT / 256) * (N_TOT / 256), 1024, 0, stream>>>(xb, wb, qp, bias, out);
}